// Round 3
// baseline (110.458 us; speedup 1.0000x reference)
//
#include <hip/hip_runtime.h>

// Problem constants: B=4, S=2048, D=1024, G=256, I=1024, H=16
#define BB 4
#define SS 2048
#define DD 1024
#define II 1024

// Algebraic collapse (verified rounds 1-4): keys identical across seq ->
// softmax uniform -> out[b,s,:] = ((mean_s x[b,s,:]) @ Wv) @ Wo broadcast
// over s. Wq/Wk/structure_features unused.
//
// Round 6 post-mortem: cooperative grid.sync costs ~55 us/sync on gfx950
// (cross-XCD coherence) -> fused single-kernel 2.1x SLOWER. 5-kernel pipeline
// restored round 7 (109.4 us = 84.5 fills + ~14.5 work + ~10.4 boundaries).
//
// Round 8: fuse the broadcast (k4) into the second GEMV -- the block that
// computes orow[b][i0:i0+16] broadcasts it to out[b][:][i0:i0+16] itself.
// Wave store pattern: 4 consecutive s x 16 cols = four 64 B segments =
// HBM3E pseudo-channel granularity (full rate, same shape as W loads).
// Saves one dispatch boundary (~1.7 us) + the orow round-trip.
//   k1   (512 blk x  256): x -> pbuf[4][128][1024]   NT loads  (~5.4 us, BW)
//   kred ( 64 blk x  256): pbuf -> xbar                         (~0.5 us)
//   kg1  (256 blk x 1024): tvec = xbar @ Wv                     (~0.9 us)
//   kg2o (256 blk x 1024): orow = tvec @ Wo -> bcast out        (~6.0 us, BW)

constexpr int JP = 128;            // partials per batch
constexpr int ROWS1 = SS / JP;     // 16 rows per k1 block

typedef float f4 __attribute__((ext_vector_type(4)));

// k1: pbuf[g][:] = sum of 16 consecutive rows of x  (g = b*128 + j)
__global__ __launch_bounds__(256)
void k1_partial(const f4* __restrict__ x, f4* __restrict__ pbuf) {
    const int g = blockIdx.x;                 // 512 blocks
    const f4* xr = x + (size_t)g * ROWS1 * (DD / 4) + threadIdx.x;
    f4 a = (f4)(0.f);
    #pragma unroll
    for (int r = 0; r < ROWS1; ++r)
        a += __builtin_nontemporal_load(xr + (size_t)r * (DD / 4));
    pbuf[(size_t)g * (DD / 4) + threadIdx.x] = a;
}

// kred: xbar[b][dg*64 : +64] = (1/S) * sum_j pbuf[b][j][slice]
// 64 blocks = (b, dg); thread = (jg 0..15, c4 0..15); each sums 8 j's.
__global__ __launch_bounds__(256)
void kred(const f4* __restrict__ pbuf, f4* __restrict__ xbar) {
    const int b = blockIdx.x >> 4, dg = blockIdx.x & 15;
    const int c4 = threadIdx.x & 15;          // float4 column within slice
    const int jg = threadIdx.x >> 4;          // 16 j-groups of 8
    const f4* p = pbuf + ((size_t)b * JP + jg * 8) * (DD / 4) + dg * 16 + c4;
    f4 a = (f4)(0.f);
    #pragma unroll
    for (int j = 0; j < 8; ++j)
        a += p[(size_t)j * (DD / 4)];
    __shared__ f4 red[16][16];                // 4 KB
    red[jg][c4] = a;
    __syncthreads();
    if (threadIdx.x < 16) {
        f4 s = (f4)(0.f);
        #pragma unroll
        for (int q = 0; q < 16; ++q)
            s += red[q][threadIdx.x];
        xbar[b * (DD / 4) + dg * 16 + threadIdx.x] = s * (1.0f / (float)SS);
    }
}

// kg1: tvec[b][i0:i0+16] = vec[b][:] @ Wv[:, i0:i0+16]
// 256 blocks = (b 0..3) x (cg 0..63); 1024 threads = (ks 0..63) x (il 0..15).
// All 256 CUs engaged; wave = 4 ks x 16 il -> four 64 B W-load segments.
__global__ __launch_bounds__(1024)
void kg_gemv_b(const f4* __restrict__ vec, const float* __restrict__ W,
               float* __restrict__ out) {
    __shared__ float xs[DD];                  // this block's batch row, 4 KB
    const int cg = blockIdx.x & 63;
    const int b  = blockIdx.x >> 6;
    const int tid = threadIdx.x;
    if (tid < DD / 4) ((f4*)xs)[tid] = vec[b * (DD / 4) + tid];
    __syncthreads();

    const int i0 = cg * 16;
    const int il = tid & 15, ks = tid >> 4;   // 64 k-groups of 16
    const float* wp = W + (size_t)(ks * 16) * DD + i0 + il;
    float a = 0.f;
    #pragma unroll
    for (int kk = 0; kk < 16; ++kk)
        a += xs[ks * 16 + kk] * wp[(size_t)kk * DD];

    __shared__ float red[64 * 16];            // [ks][il], 4 KB
    __shared__ float red2[4 * 16];
    red[ks * 16 + il] = a;
    __syncthreads();
    if (tid < 64) {                           // 2-stage reduce
        const int q = tid >> 4, i = tid & 15;
        float s = 0.f;
        #pragma unroll
        for (int k = 0; k < 16; ++k) s += red[(q * 16 + k) * 16 + i];
        red2[q * 16 + i] = s;
    }
    __syncthreads();
    if (tid < 16) {
        float s = red2[0 * 16 + tid] + red2[1 * 16 + tid]
                + red2[2 * 16 + tid] + red2[3 * 16 + tid];
        out[b * DD + i0 + tid] = s;
    }
}

// kg2o: orow16 = tvec[b][:] @ Wo[:, i0:i0+16], then broadcast to
// out[b][0..S)[i0:i0+16]. Thread (sg 0..63, il 0..15) writes s = sg + 64r;
// wave = 4 consecutive s x 16 cols = four 64 B segments (full HBM rate).
__global__ __launch_bounds__(1024)
void kg2_bcast(const f4* __restrict__ vec, const float* __restrict__ W,
               float* __restrict__ out) {
    __shared__ float xs[DD];
    const int cg = blockIdx.x & 63;
    const int b  = blockIdx.x >> 6;
    const int tid = threadIdx.x;
    if (tid < DD / 4) ((f4*)xs)[tid] = vec[b * (DD / 4) + tid];
    __syncthreads();

    const int i0 = cg * 16;
    const int il = tid & 15, ks = tid >> 4;
    const float* wp = W + (size_t)(ks * 16) * DD + i0 + il;
    float a = 0.f;
    #pragma unroll
    for (int kk = 0; kk < 16; ++kk)
        a += xs[ks * 16 + kk] * wp[(size_t)kk * DD];

    __shared__ float red[64 * 16];
    __shared__ float red2[4 * 16];
    __shared__ float orow16[16];
    red[ks * 16 + il] = a;
    __syncthreads();
    if (tid < 64) {
        const int q = tid >> 4, i = tid & 15;
        float s = 0.f;
        #pragma unroll
        for (int k = 0; k < 16; ++k) s += red[(q * 16 + k) * 16 + i];
        red2[q * 16 + i] = s;
    }
    __syncthreads();
    if (tid < 16)
        orow16[tid] = red2[0 * 16 + tid] + red2[1 * 16 + tid]
                    + red2[2 * 16 + tid] + red2[3 * 16 + tid];
    __syncthreads();

    // broadcast: thread (sg = tid>>4, il) writes col i0+il at s = sg + 64r
    const float c = orow16[il];
    const int sg = tid >> 4;
    float* o = out + (size_t)b * SS * DD + (size_t)sg * DD + i0 + il;
    #pragma unroll
    for (int r = 0; r < SS / 64; ++r)
        __builtin_nontemporal_store(c, o + (size_t)r * 64 * DD);
}

extern "C" void kernel_launch(void* const* d_in, const int* in_sizes, int n_in,
                              void* d_out, int out_size, void* d_ws, size_t ws_size,
                              hipStream_t stream) {
    const float* x  = (const float*)d_in[0];  // inputs_embeds [B,S,D]
    const float* Wv = (const float*)d_in[4];  // [D,I]
    const float* Wo = (const float*)d_in[5];  // [I,D]
    float* out = (float*)d_out;

    float* pbuf = (float*)d_ws;                       // BB*JP*DD floats (2 MB)
    float* xbar = pbuf + (size_t)BB * JP * DD;        // [4][1024]
    float* tvec = xbar + (size_t)BB * DD;             // [4][1024]

    k1_partial<<<BB * JP, 256, 0, stream>>>((const f4*)x, (f4*)pbuf);
    kred<<<64, 256, 0, stream>>>((const f4*)pbuf, (f4*)xbar);
    kg_gemv_b<<<256, 1024, 0, stream>>>((const f4*)xbar, Wv, tvec);
    kg2_bcast<<<256, 1024, 0, stream>>>((const f4*)tvec, Wo, out);
}